// Round 1
// 952.142 us; speedup vs baseline: 1.6722x; 1.6722x over previous
//
#include <hip/hip_runtime.h>

// ---------------------------------------------------------------------------
// SpatialAttention3D: B=2, C=384, D=H=W=32, HEADS=12, HD=32, WS=5, PAD=2
// I/O dtype: float32. Intermediates q/k/v/a: bf16.
// R6: attn3d rewritten on MFMA.
//   Per block: one 4x4x4 query tile (64 q), halo 8x8x8 = 512 keys, 4 waves.
//   Wave w owns query z-slice w (16 queries). Halo processed in 4 chunks of
//   128 keys (2 z-layers each):
//     S^T[key][q]  = mfma(A=K[key][c], B=Q[q][c])        (same frag convention
//     QPE^T[n][q]  = mfma(A=PE[n][c],  B=Q[q][c])         as verified qkv_mfma)
//     O^T[hd][q]   = mfma(A=V^T[hd][k], B=P[q][k])
//   Online softmax over chunks; window mask + qpe bias gathered per element.
//   Wave-uniform chunk/tile skipping via dz validity (saves ~40% of S/PV).
//   LDS 58.9 KB -> 2 blocks/CU (8 waves/CU vs 4 before).
// qkv_mfma / proj_mfma unchanged from R5.
// ---------------------------------------------------------------------------

#define NB 2
#define NC 384
#define NHEADS 12
#define NHD 32
#define NS 32768               // 32*32*32
#define PERB 12582912          // NC*NS (one batch of out / qkv third)
#define SCALE_F 0.17677669529663687f
#define LOG2E_F 1.4426950408889634f

typedef unsigned short bfr;    // raw bf16 bits
typedef float floatx4 __attribute__((ext_vector_type(4)));
typedef float f32x4 __attribute__((ext_vector_type(4)));
typedef short bf16x8 __attribute__((ext_vector_type(8)));   // 8 bf16 = 1 b128
typedef short short4v __attribute__((ext_vector_type(4)));  // 4 bf16 = 1 b64

union B8 { floatx4 v; bfr h[8]; };

// pel (QPE prologue) and pl (P chunks, per-wave) never live simultaneously.
union PU {
    bfr pel[128][40];      // pe transposed [n][hd]; rows 125..127 zeroed
    bfr pl[4][16][136];    // per-wave P chunk, [q][k] row-major
};

__device__ __forceinline__ float b2f(bfr u) {
    union { unsigned int i; float f; } v;
    v.i = (unsigned int)u << 16;
    return v.f;
}
__device__ __forceinline__ bfr f2b(float f) {
    union { float f; unsigned int i; } v;
    v.f = f;
    unsigned int x = v.i;
    return (bfr)((x + 0x7fffu + ((x >> 16) & 1u)) >> 16);  // RNE
}

// diagnostic: encode ws_size (MiB) into the output if ws is too small
__global__ void fill_code(float* out, float code) {
    for (size_t i = (size_t)blockIdx.x*256 + threadIdx.x; i < (size_t)NB*PERB;
         i += (size_t)gridDim.x*256) out[i] = code;
}

// ---------------------------------------------------------------------------
// Kernel 1: QKV GEMM, MFMA. grid (256 s-tiles, 9 o-tiles), 256 threads.
// o-blocks 0..2 -> q, 3..5 -> k, 6..8 -> v (128 o = 4 heads each, exact).
// ---------------------------------------------------------------------------
__global__ __launch_bounds__(256) void qkv_mfma(
    const float* __restrict__ x, const float* __restrict__ w,
    const float* __restrict__ bias,
    bfr* __restrict__ qT, bfr* __restrict__ kT, bfr* __restrict__ vT, int b)
{
    __shared__ __attribute__((aligned(16))) bfr wl[128*40];   // [o][c] pad40
    __shared__ __attribute__((aligned(16))) bfr xl[128*40];   // [s][c] pad40
    __shared__ float bsh[128];
    const int tid  = threadIdx.x;
    const int lane = tid & 63;
    const int wave = tid >> 6;
    const int wo   = (wave & 1) * 64;     // wave o-quadrant
    const int wsq  = (wave >> 1) * 64;    // wave s-quadrant
    const int s0   = blockIdx.x * 128;
    const int o0   = blockIdx.y * 128;
    const int m16  = lane & 15;           // fragment row/col index
    const int g    = lane >> 4;           // k-chunk quarter (0..3)

    if (tid < 128) bsh[tid] = bias[o0 + tid];

    f32x4 acc[4][4];
    #pragma unroll
    for (int i = 0; i < 4; ++i)
        #pragma unroll
        for (int j = 0; j < 4; ++j) acc[i][j] = (f32x4){0.f, 0.f, 0.f, 0.f};

    for (int kc = 0; kc < 12; ++kc) {
        const int c0 = kc * 32;
        // stage w tile [128 o][32 c] f32->bf16 (1024 float4, 4 per thread)
        #pragma unroll
        for (int r = 0; r < 4; ++r) {
            const int idx = r*256 + tid;
            const int o   = idx >> 3;
            const int c4  = (idx & 7) * 4;
            floatx4 wv = *(const floatx4*)&w[(size_t)(o0 + o)*NC + c0 + c4];
            short4v t;
            t[0] = (short)f2b(wv[0]); t[1] = (short)f2b(wv[1]);
            t[2] = (short)f2b(wv[2]); t[3] = (short)f2b(wv[3]);
            *(short4v*)&wl[o*40 + c4] = t;
        }
        // stage x tile transposed: [32 c][128 s] f32 -> LDS [s][c] bf16
        #pragma unroll
        for (int r = 0; r < 4; ++r) {
            const int idx = r*256 + tid;
            const int c   = idx >> 5;
            const int s4  = (idx & 31) * 4;
            floatx4 xv =
                *(const floatx4*)&x[((size_t)b*NC + c0 + c)*NS + s0 + s4];
            #pragma unroll
            for (int i = 0; i < 4; ++i) xl[(s4 + i)*40 + c] = f2b(xv[i]);
        }
        __syncthreads();
        bf16x8 af[4], bfg[4];
        #pragma unroll
        for (int i = 0; i < 4; ++i)
            af[i] = *(bf16x8*)&wl[(wo + i*16 + m16)*40 + g*8];
        #pragma unroll
        for (int j = 0; j < 4; ++j)
            bfg[j] = *(bf16x8*)&xl[(wsq + j*16 + m16)*40 + g*8];
        #pragma unroll
        for (int i = 0; i < 4; ++i)
            #pragma unroll
            for (int j = 0; j < 4; ++j)
                acc[i][j] = __builtin_amdgcn_mfma_f32_16x16x32_bf16(
                    af[i], bfg[j], acc[i][j], 0, 0, 0);
        __syncthreads();
    }

    // epilogue: +bias, bf16, heads layout. tensor uniform per block.
    const int tens = blockIdx.y / 3;            // 0=q,1=k,2=v
    bfr* dstT = (tens == 0) ? qT : ((tens == 1) ? kT : vT);
    const int remb = o0 - tens*NC;              // o offset within tensor
    const int q4   = g * 4;                     // C-layout row group
    #pragma unroll
    for (int i = 0; i < 4; ++i) {
        const int olb = wo + i*16 + q4;         // block-local o (mult of 4)
        const int ob  = remb + olb;
        const int hh  = ob >> 5;
        const int cc  = ob & 31;
        #pragma unroll
        for (int j = 0; j < 4; ++j) {
            const int s = s0 + wsq + j*16 + m16;
            short4v t;
            #pragma unroll
            for (int r = 0; r < 4; ++r)
                t[r] = (short)f2b(acc[i][j][r] + bsh[olb + r]);
            *(short4v*)&dstT[((size_t)hh*NS + s)*NHD + cc] = t;
        }
    }
}

// ---------------------------------------------------------------------------
// Kernel 2: attn3d — MFMA rewrite. grid (512 tiles, 12 heads), 256 threads.
// ---------------------------------------------------------------------------
__global__ __launch_bounds__(256) void attn3d(
    const bfr* __restrict__ qT, const bfr* __restrict__ kT,
    const bfr* __restrict__ vT, const float* __restrict__ pe,
    bfr* __restrict__ aT)
{
    __shared__ __attribute__((aligned(16))) bfr kl[128][40];    // K chunk [key][c]
    __shared__ __attribute__((aligned(16))) bfr vtl[32][136];   // V chunk [hd][key]
    __shared__ __attribute__((aligned(16))) bfr ql[64][40];     // Q tile [q][c]
    __shared__ __attribute__((aligned(16))) bfr qpl[64][136];   // qpe*SCALE [q][n]
    __shared__ __attribute__((aligned(16))) PU  up;             // pel / pl

    const int tid  = threadIdx.x;
    const int lane = tid & 63;
    const int wave = tid >> 6;            // = qz of this wave's queries
    const int m16  = lane & 15;
    const int g    = lane >> 4;
    const int g4   = g << 2;
    const int bx   = blockIdx.x;
    const int tz = bx >> 6, ty = (bx >> 3) & 7, tx = bx & 7;
    const size_t hb = (size_t)blockIdx.y * NS;

    // ---- stage Q tile (one b128 per thread) ----
    {
        const int qr = tid >> 2, part = tid & 3;
        const int qzr = qr >> 4, qyr = (qr >> 2) & 3, qxr = qr & 3;
        const size_t sq =
            (size_t)(tz*4 + qzr)*1024 + (ty*4 + qyr)*32 + (tx*4 + qxr);
        *(floatx4*)&ql[qr][part*8] =
            *(const floatx4*)&qT[(hb + sq)*NHD + part*8];
    }
    // ---- stage pe transposed: pe[hd*125+n] -> pel[n][hd] bf16 ----
    for (int e = tid; e < 4000; e += 256) {
        const int hd = e / 125;
        const int n  = e - hd*125;
        up.pel[n][hd] = f2b(pe[e]);
    }
    if (tid < 96) up.pel[125 + (tid >> 5)][tid & 31] = 0;
    __syncthreads();

    // ---- Q B-fragment (reused by QPE and all S chunks) ----
    const int wq = wave*16 + m16;                 // this lane's query row
    const bf16x8 bq = *(const bf16x8*)&ql[wq][g*8];

    // ---- QPE^T[n][q] = PE . Q^T, written (pre-scaled) to qpl[q][n] ----
    #pragma unroll
    for (int t = 0; t < 8; ++t) {
        bf16x8 pa = *(const bf16x8*)&up.pel[t*16 + m16][g*8];
        f32x4 qa = __builtin_amdgcn_mfma_f32_16x16x32_bf16(
            pa, bq, (f32x4){0.f, 0.f, 0.f, 0.f}, 0, 0, 0);
        const unsigned w0 = (unsigned)f2b(qa[0]*SCALE_F) |
                            ((unsigned)f2b(qa[1]*SCALE_F) << 16);
        const unsigned w1 = (unsigned)f2b(qa[2]*SCALE_F) |
                            ((unsigned)f2b(qa[3]*SCALE_F) << 16);
        *(uint2*)&qpl[wq][t*16 + g4] = make_uint2(w0, w1);
    }

    const int qy = (m16 >> 2), qx = m16 & 3;      // lane's query y/x
    float m = -1e30f, l = 0.f;
    f32x4 o[2];
    o[0] = (f32x4){0.f, 0.f, 0.f, 0.f};
    o[1] = (f32x4){0.f, 0.f, 0.f, 0.f};

    for (int c = 0; c < 4; ++c) {
        __syncthreads();   // prev-chunk reads done (and pel free before pl use)
        // ---- stage K chunk: 128 keys x 32 c, zero-padded OOB ----
        #pragma unroll
        for (int r2 = 0; r2 < 2; ++r2) {
            const int idx = r2*256 + tid;
            const int key = idx >> 2, part = idx & 3;
            const int hz = 2*c + (key >> 6), hy = (key >> 3) & 7, hx = key & 7;
            const int gz = tz*4 - 2 + hz, gy = ty*4 - 2 + hy, gx = tx*4 - 2 + hx;
            floatx4 kv = (floatx4){0.f, 0.f, 0.f, 0.f};
            if ((unsigned)gz < 32u && (unsigned)gy < 32u && (unsigned)gx < 32u)
                kv = *(const floatx4*)
                     &kT[(hb + gz*1024 + gy*32 + gx)*NHD + part*8];
            *(floatx4*)&kl[key][part*8] = kv;
        }
        // ---- stage V chunk transposed: [key][hd] -> vtl[hd][key] ----
        {
            const int key = tid >> 1, hh = (tid & 1) * 16;
            const int hz = 2*c + (key >> 6), hy = (key >> 3) & 7, hx = key & 7;
            const int gz = tz*4 - 2 + hz, gy = ty*4 - 2 + hy, gx = tx*4 - 2 + hx;
            B8 a, b;
            a.v = (floatx4){0.f, 0.f, 0.f, 0.f};
            b.v = (floatx4){0.f, 0.f, 0.f, 0.f};
            if ((unsigned)gz < 32u && (unsigned)gy < 32u && (unsigned)gx < 32u) {
                const size_t gi = hb + gz*1024 + gy*32 + gx;
                a.v = *(const floatx4*)&vT[gi*NHD + hh];
                b.v = *(const floatx4*)&vT[gi*NHD + hh + 8];
            }
            #pragma unroll
            for (int i = 0; i < 8; ++i) vtl[hh + i][key] = a.h[i];
            #pragma unroll
            for (int i = 0; i < 8; ++i) vtl[hh + 8 + i][key] = b.h[i];
        }
        __syncthreads();   // chunk staged

        // ---- wave-uniform z-window validity for the 2 halo z-layers ----
        const bool v0 = (unsigned)(2*c     - wave) <= 4u;
        const bool v1 = (unsigned)(2*c + 1 - wave) <= 4u;
        if (!v0 && !v1) continue;   // barriers stay outside; safe

        // ---- S^T = K . Q^T for valid 16-key tiles ----
        f32x4 s[8];
        #pragma unroll
        for (int t = 0; t < 8; ++t) {
            if ((t < 4) ? v0 : v1) {
                bf16x8 ka = *(const bf16x8*)&kl[t*16 + m16][g*8];
                s[t] = __builtin_amdgcn_mfma_f32_16x16x32_bf16(
                    ka, bq, (f32x4){0.f, 0.f, 0.f, 0.f}, 0, 0, 0);
            }
        }
        // ---- masked, biased scores + chunk max ----
        float sv[8][4];
        float mx = -1e30f;
        #pragma unroll
        for (int t = 0; t < 8; ++t) {
            const bool tv = (t < 4) ? v0 : v1;
            if (!tv) continue;
            const int nz = (2*c + (t >> 2) - wave) * 25;   // dz*25, dz in [0,4]
            #pragma unroll
            for (int r = 0; r < 4; ++r) {
                const int t0 = g4 + r;                     // key mod 16
                const int hy = 2*(t & 3) + (t0 >> 3);
                const int hx = t0 & 7;
                const int dy = hy - qy, dx = hx - qx;
                const bool ok = ((unsigned)dy < 5u) && ((unsigned)dx < 5u);
                const int  n  = ok ? (nz + dy*5 + dx) : 0;
                const float qb  = b2f(qpl[wq][n]);
                const float val = ok ? fmaf(s[t][r], SCALE_F, qb) : -1e30f;
                sv[t][r] = val;
                mx = fmaxf(mx, val);
            }
        }
        mx = fmaxf(mx, __shfl_xor(mx, 16));
        mx = fmaxf(mx, __shfl_xor(mx, 32));
        const float mn = fmaxf(m, mx);
        const float al = exp2f((m - mn) * LOG2E_F);
        m = mn;
        // ---- P = exp(S - m), bf16, to wave-private LDS ----
        float ls = 0.f;
        #pragma unroll
        for (int t = 0; t < 8; ++t) {
            const bool tv = (t < 4) ? v0 : v1;
            if (!tv) continue;
            const float p0 = exp2f((sv[t][0] - mn) * LOG2E_F);
            const float p1 = exp2f((sv[t][1] - mn) * LOG2E_F);
            const float p2 = exp2f((sv[t][2] - mn) * LOG2E_F);
            const float p3 = exp2f((sv[t][3] - mn) * LOG2E_F);
            ls += (p0 + p1) + (p2 + p3);
            const unsigned w0 = (unsigned)f2b(p0) | ((unsigned)f2b(p1) << 16);
            const unsigned w1 = (unsigned)f2b(p2) | ((unsigned)f2b(p3) << 16);
            *(uint2*)&up.pl[wave][m16][t*16 + g4] = make_uint2(w0, w1);
        }
        ls += __shfl_xor(ls, 16);
        ls += __shfl_xor(ls, 32);
        l = l * al + ls;
        #pragma unroll
        for (int i = 0; i < 4; ++i) { o[0][i] *= al; o[1][i] *= al; }
        // ---- O^T += V^T . P^T over valid 32-key k-steps ----
        #pragma unroll
        for (int ks = 0; ks < 4; ++ks) {
            if ((ks < 2) ? v0 : v1) {
                bf16x8 pb = *(const bf16x8*)&up.pl[wave][m16][ks*32 + g*8];
                #pragma unroll
                for (int mt = 0; mt < 2; ++mt) {
                    bf16x8 va = *(const bf16x8*)&vtl[mt*16 + m16][ks*32 + g*8];
                    o[mt] = __builtin_amdgcn_mfma_f32_16x16x32_bf16(
                        va, pb, o[mt], 0, 0, 0);
                }
            }
        }
    }

    // ---- normalize + store: lane holds O^T[hd = mt*16+g4+r][q = wq] ----
    const float rl = 1.f / l;
    const size_t sq = (size_t)(tz*4 + wave)*1024 + (ty*4 + qy)*32 + (tx*4 + qx);
    #pragma unroll
    for (int mt = 0; mt < 2; ++mt) {
        const unsigned w0 = (unsigned)f2b(o[mt][0]*rl) |
                            ((unsigned)f2b(o[mt][1]*rl) << 16);
        const unsigned w1 = (unsigned)f2b(o[mt][2]*rl) |
                            ((unsigned)f2b(o[mt][3]*rl) << 16);
        *(uint2*)&aT[(hb + sq)*NHD + mt*16 + g4] = make_uint2(w0, w1);
    }
}

// ---------------------------------------------------------------------------
// Kernel 3: proj GEMM, MFMA. grid (256 s-tiles, 3 o-tiles), 256 threads.
// B operand (aT) is already [s][c]-contiguous per head -> pure b128 staging.
// ---------------------------------------------------------------------------
__global__ __launch_bounds__(256) void proj_mfma(
    const bfr* __restrict__ aT, const float* __restrict__ w,
    const float* __restrict__ bias, float* __restrict__ out)
{
    __shared__ __attribute__((aligned(16))) bfr wl[128*40];   // [o][c] pad40
    __shared__ __attribute__((aligned(16))) bfr xl[128*40];   // [s][c] pad40
    __shared__ float bsh[128];
    const int tid  = threadIdx.x;
    const int lane = tid & 63;
    const int wave = tid >> 6;
    const int wo   = (wave & 1) * 64;
    const int wsq  = (wave >> 1) * 64;
    const int s0   = blockIdx.x * 128;
    const int o0   = blockIdx.y * 128;
    const int m16  = lane & 15;
    const int g    = lane >> 4;

    if (tid < 128) bsh[tid] = bias[o0 + tid];

    f32x4 acc[4][4];
    #pragma unroll
    for (int i = 0; i < 4; ++i)
        #pragma unroll
        for (int j = 0; j < 4; ++j) acc[i][j] = (f32x4){0.f, 0.f, 0.f, 0.f};

    for (int kc = 0; kc < 12; ++kc) {          // kc == head
        const int c0 = kc * 32;
        // stage w tile [128 o][32 c] f32->bf16
        #pragma unroll
        for (int r = 0; r < 4; ++r) {
            const int idx = r*256 + tid;
            const int o   = idx >> 3;
            const int c4  = (idx & 7) * 4;
            floatx4 wv = *(const floatx4*)&w[(size_t)(o0 + o)*NC + c0 + c4];
            short4v t;
            t[0] = (short)f2b(wv[0]); t[1] = (short)f2b(wv[1]);
            t[2] = (short)f2b(wv[2]); t[3] = (short)f2b(wv[3]);
            *(short4v*)&wl[o*40 + c4] = t;
        }
        // stage a tile: [128 s][32 c] bf16, direct b128 copies (512, 2/thread)
        #pragma unroll
        for (int r = 0; r < 2; ++r) {
            const int idx = r*256 + tid;
            const int s   = idx >> 2;
            const int gg  = idx & 3;
            *(floatx4*)&xl[s*40 + gg*8] =
                *(const floatx4*)&aT[((size_t)kc*NS + s0 + s)*NHD + gg*8];
        }
        __syncthreads();
        bf16x8 af[4], bfg[4];
        #pragma unroll
        for (int i = 0; i < 4; ++i)
            af[i] = *(bf16x8*)&wl[(wo + i*16 + m16)*40 + g*8];
        #pragma unroll
        for (int j = 0; j < 4; ++j)
            bfg[j] = *(bf16x8*)&xl[(wsq + j*16 + m16)*40 + g*8];
        #pragma unroll
        for (int i = 0; i < 4; ++i)
            #pragma unroll
            for (int j = 0; j < 4; ++j)
                acc[i][j] = __builtin_amdgcn_mfma_f32_16x16x32_bf16(
                    af[i], bfg[j], acc[i][j], 0, 0, 0);
        __syncthreads();
    }

    // epilogue: +bias, f32 channel-major out[o][s]
    const int q4 = g * 4;
    #pragma unroll
    for (int i = 0; i < 4; ++i) {
        const int olb = wo + i*16 + q4;
        #pragma unroll
        for (int j = 0; j < 4; ++j) {
            const int s = s0 + wsq + j*16 + m16;
            #pragma unroll
            for (int r = 0; r < 4; ++r)
                out[(size_t)(o0 + olb + r)*NS + s] = acc[i][j][r] + bsh[olb + r];
        }
    }
}

// ---------------------------------------------------------------------------
extern "C" void kernel_launch(void* const* d_in, const int* in_sizes, int n_in,
                              void* d_out, int out_size, void* d_ws, size_t ws_size,
                              hipStream_t stream)
{
    const float* x      = (const float*)d_in[0];
    const float* w_qkv  = (const float*)d_in[1];
    const float* b_qkv  = (const float*)d_in[2];
    const float* w_proj = (const float*)d_in[3];
    const float* b_proj = (const float*)d_in[4];
    const float* pe     = (const float*)d_in[5];
    float* outp = (float*)d_out;

    const size_t NEED = (size_t)2 * PERB * sizeof(bfr);  // 48 MiB
    if (ws_size < NEED) {
        fill_code<<<2048, 256, 0, stream>>>(outp, (float)(ws_size >> 20));
        return;
    }

    bfr* qT = (bfr*)d_ws;          // ws[0 .. PERB)      (aT aliases this)
    bfr* vT = qT + PERB;           // ws[PERB .. 2*PERB)

    for (int b = 0; b < NB; ++b) {
        bfr* kT = (bfr*)(outp + (size_t)b * PERB);  // d_out batch half
        bfr* aT = qT;
        qkv_mfma<<<dim3(256, 9, 1), 256, 0, stream>>>(
            x, w_qkv, b_qkv, qT, kT, vT, b);
        attn3d<<<dim3(512, 12, 1), 256, 0, stream>>>(qT, kT, vT, pe, aT);
        proj_mfma<<<dim3(256, 3, 1), 256, 0, stream>>>(
            aT, w_proj, b_proj, outp + (size_t)b * PERB);
    }
}

// Round 2
// 713.268 us; speedup vs baseline: 2.2322x; 1.3349x over previous
//
#include <hip/hip_runtime.h>

// ---------------------------------------------------------------------------
// SpatialAttention3D: B=2, C=384, D=H=W=32, HEADS=12, HD=32, WS=5, PAD=2
// I/O dtype: float32. Intermediates q/k/v/a: bf16.
// R7: attn3d occupancy + LDS-traffic rework (qkv/proj unchanged from R5).
//   - LDS exactly 40960 B -> 4 blocks/CU (was 58880 -> 2 blocks/CU):
//       kl[128][40] (K chunk)  \___ overlaid by pel[128][40] (prologue only)
//       vtl[32][136] (V^T chunk)/
//       ql[64][40] (Q tile), qpl[64][132] (qpe*SCALE*log2e + -inf sentinel)
//   - P never goes to LDS: PV B-frag built with ds_bpermute lane shuffles.
//   - V^T staging: key-pair packed b32 writes, conflict-free (was 32x b16).
//   - Window mask folded into gather: n = min(nz+no, 128), qpl[:,128] = -inf.
//   - Per-z-layer online softmax (5 valid layers/wave, uniform), setprio
//     around MFMA clusters, log2-domain scores.
// ---------------------------------------------------------------------------

#define NB 2
#define NC 384
#define NHEADS 12
#define NHD 32
#define NS 32768               // 32*32*32
#define PERB 12582912          // NC*NS (one batch of out / qkv third)
#define SCALE_F 0.17677669529663687f
#define LOG2E_F 1.4426950408889634f
#define SL_F (0.17677669529663687f * 1.4426950408889634f)   // SCALE*log2e

typedef unsigned short bfr;    // raw bf16 bits
typedef float floatx4 __attribute__((ext_vector_type(4)));
typedef float f32x4 __attribute__((ext_vector_type(4)));
typedef short bf16x8 __attribute__((ext_vector_type(8)));   // 8 bf16 = 1 b128
typedef short short4v __attribute__((ext_vector_type(4)));  // 4 bf16 = 1 b64

union B8 { floatx4 v; bfr h[8]; };

__device__ __forceinline__ float b2f(bfr u) {
    union { unsigned int i; float f; } v;
    v.i = (unsigned int)u << 16;
    return v.f;
}
__device__ __forceinline__ bfr f2b(float f) {
    union { float f; unsigned int i; } v;
    v.f = f;
    unsigned int x = v.i;
    return (bfr)((x + 0x7fffu + ((x >> 16) & 1u)) >> 16);  // RNE
}

// diagnostic: encode ws_size (MiB) into the output if ws is too small
__global__ void fill_code(float* out, float code) {
    for (size_t i = (size_t)blockIdx.x*256 + threadIdx.x; i < (size_t)NB*PERB;
         i += (size_t)gridDim.x*256) out[i] = code;
}

// ---------------------------------------------------------------------------
// Kernel 1: QKV GEMM, MFMA. grid (256 s-tiles, 9 o-tiles), 256 threads.
// ---------------------------------------------------------------------------
__global__ __launch_bounds__(256) void qkv_mfma(
    const float* __restrict__ x, const float* __restrict__ w,
    const float* __restrict__ bias,
    bfr* __restrict__ qT, bfr* __restrict__ kT, bfr* __restrict__ vT, int b)
{
    __shared__ __attribute__((aligned(16))) bfr wl[128*40];   // [o][c] pad40
    __shared__ __attribute__((aligned(16))) bfr xl[128*40];   // [s][c] pad40
    __shared__ float bsh[128];
    const int tid  = threadIdx.x;
    const int lane = tid & 63;
    const int wave = tid >> 6;
    const int wo   = (wave & 1) * 64;     // wave o-quadrant
    const int wsq  = (wave >> 1) * 64;    // wave s-quadrant
    const int s0   = blockIdx.x * 128;
    const int o0   = blockIdx.y * 128;
    const int m16  = lane & 15;           // fragment row/col index
    const int g    = lane >> 4;           // k-chunk quarter (0..3)

    if (tid < 128) bsh[tid] = bias[o0 + tid];

    f32x4 acc[4][4];
    #pragma unroll
    for (int i = 0; i < 4; ++i)
        #pragma unroll
        for (int j = 0; j < 4; ++j) acc[i][j] = (f32x4){0.f, 0.f, 0.f, 0.f};

    for (int kc = 0; kc < 12; ++kc) {
        const int c0 = kc * 32;
        // stage w tile [128 o][32 c] f32->bf16 (1024 float4, 4 per thread)
        #pragma unroll
        for (int r = 0; r < 4; ++r) {
            const int idx = r*256 + tid;
            const int o   = idx >> 3;
            const int c4  = (idx & 7) * 4;
            floatx4 wv = *(const floatx4*)&w[(size_t)(o0 + o)*NC + c0 + c4];
            short4v t;
            t[0] = (short)f2b(wv[0]); t[1] = (short)f2b(wv[1]);
            t[2] = (short)f2b(wv[2]); t[3] = (short)f2b(wv[3]);
            *(short4v*)&wl[o*40 + c4] = t;
        }
        // stage x tile transposed: [32 c][128 s] f32 -> LDS [s][c] bf16
        #pragma unroll
        for (int r = 0; r < 4; ++r) {
            const int idx = r*256 + tid;
            const int c   = idx >> 5;
            const int s4  = (idx & 31) * 4;
            floatx4 xv =
                *(const floatx4*)&x[((size_t)b*NC + c0 + c)*NS + s0 + s4];
            #pragma unroll
            for (int i = 0; i < 4; ++i) xl[(s4 + i)*40 + c] = f2b(xv[i]);
        }
        __syncthreads();
        bf16x8 af[4], bfg[4];
        #pragma unroll
        for (int i = 0; i < 4; ++i)
            af[i] = *(bf16x8*)&wl[(wo + i*16 + m16)*40 + g*8];
        #pragma unroll
        for (int j = 0; j < 4; ++j)
            bfg[j] = *(bf16x8*)&xl[(wsq + j*16 + m16)*40 + g*8];
        #pragma unroll
        for (int i = 0; i < 4; ++i)
            #pragma unroll
            for (int j = 0; j < 4; ++j)
                acc[i][j] = __builtin_amdgcn_mfma_f32_16x16x32_bf16(
                    af[i], bfg[j], acc[i][j], 0, 0, 0);
        __syncthreads();
    }

    // epilogue: +bias, bf16, heads layout. tensor uniform per block.
    const int tens = blockIdx.y / 3;            // 0=q,1=k,2=v
    bfr* dstT = (tens == 0) ? qT : ((tens == 1) ? kT : vT);
    const int remb = o0 - tens*NC;              // o offset within tensor
    const int q4   = g * 4;                     // C-layout row group
    #pragma unroll
    for (int i = 0; i < 4; ++i) {
        const int olb = wo + i*16 + q4;         // block-local o (mult of 4)
        const int ob  = remb + olb;
        const int hh  = ob >> 5;
        const int cc  = ob & 31;
        #pragma unroll
        for (int j = 0; j < 4; ++j) {
            const int s = s0 + wsq + j*16 + m16;
            short4v t;
            #pragma unroll
            for (int r = 0; r < 4; ++r)
                t[r] = (short)f2b(acc[i][j][r] + bsh[olb + r]);
            *(short4v*)&dstT[((size_t)hh*NS + s)*NHD + cc] = t;
        }
    }
}

// ---------------------------------------------------------------------------
// Kernel 2: attn3d — R7. grid (512 tiles, 12 heads), 256 threads.
// ---------------------------------------------------------------------------
__global__ __launch_bounds__(256, 4) void attn3d(
    const bfr* __restrict__ qT, const bfr* __restrict__ kT,
    const bfr* __restrict__ vT, const float* __restrict__ pe,
    bfr* __restrict__ aT)
{
    // exact-fit 40960 B -> 4 blocks/CU
    __shared__ __attribute__((aligned(16))) unsigned char smem[40960];
    bfr (*kl)[40]   = reinterpret_cast<bfr(*)[40]>(smem);          // [128][40]
    bfr (*vtl)[136] = reinterpret_cast<bfr(*)[136]>(smem + 10240); // [32][136]
    bfr (*pel)[40]  = reinterpret_cast<bfr(*)[40]>(smem);          // overlay
    bfr (*ql)[40]   = reinterpret_cast<bfr(*)[40]>(smem + 18944);  // [64][40]
    bfr (*qpl)[132] = reinterpret_cast<bfr(*)[132]>(smem + 24064); // [64][132]

    const int tid  = threadIdx.x;
    const int lane = tid & 63;
    const int wave = tid >> 6;            // wave = qz within tile
    const int m16  = lane & 15;
    const int g    = lane >> 4;
    const int g4   = g << 2;
    const int bx   = blockIdx.x;
    const int tz = bx >> 6, ty = (bx >> 3) & 7, tx = bx & 7;
    const size_t hb = (size_t)blockIdx.y * NS;

    // ---- stage Q tile (one b128 per thread) ----
    {
        const int qr = tid >> 2, part = tid & 3;
        const int qzr = qr >> 4, qyr = (qr >> 2) & 3, qxr = qr & 3;
        const size_t sq =
            (size_t)(tz*4 + qzr)*1024 + (ty*4 + qyr)*32 + (tx*4 + qxr);
        *(floatx4*)&ql[qr][part*8] =
            *(const floatx4*)&qT[(hb + sq)*NHD + part*8];
    }
    // ---- stage pe transposed into overlay: pe[hd*125+n] -> pel[n][hd] ----
    for (int e = tid; e < 4000; e += 256) {
        const int hd = e / 125;
        const int n  = e - hd*125;
        pel[n][hd] = f2b(pe[e]);
    }
    if (tid < 96) pel[125 + (tid >> 5)][tid & 31] = 0;
    __syncthreads();

    const int wq = wave*16 + m16;                 // this lane's query row
    const bf16x8 bq = *(const bf16x8*)&ql[wq][g*8];

    // ---- QPE^T[n][q] = PE . Q^T, pre-scaled by SCALE*log2e -> qpl[q][n] ----
    #pragma unroll
    for (int t = 0; t < 8; ++t) {
        bf16x8 pa = *(const bf16x8*)&pel[t*16 + m16][g*8];
        f32x4 qa = __builtin_amdgcn_mfma_f32_16x16x32_bf16(
            pa, bq, (f32x4){0.f, 0.f, 0.f, 0.f}, 0, 0, 0);
        const unsigned w0 = (unsigned)f2b(qa[0]*SL_F) |
                            ((unsigned)f2b(qa[1]*SL_F) << 16);
        const unsigned w1 = (unsigned)f2b(qa[2]*SL_F) |
                            ((unsigned)f2b(qa[3]*SL_F) << 16);
        *(uint2*)&qpl[wq][t*16 + g4] = make_uint2(w0, w1);
    }
    if (g == 0) qpl[wq][128] = 0xFF80u;           // -inf sentinel column

    // ---- per-lane window table no[tt][r], packed 4x u8 per reg ----
    const int qy = m16 >> 2, qx = m16 & 3;
    unsigned nopk[4];
    #pragma unroll
    for (int tt = 0; tt < 4; ++tt) {
        unsigned v = 0;
        #pragma unroll
        for (int r = 0; r < 4; ++r) {
            const int t0 = g4 + r;
            const int hy = 2*tt + (t0 >> 3), hx = t0 & 7;
            const int dy = hy - qy, dx = hx - qx;
            const bool ok = ((unsigned)dy < 5u) && ((unsigned)dx < 5u);
            v |= (unsigned)(ok ? (dy*5 + dx) : 128) << (8*r);
        }
        nopk[tt] = v;
    }
    const bfr* qprow = qpl[wq];
    // bpermute byte-addrs for P redistribution (derivation in PV loop below)
    const int a0 = (m16 + 32*(g & 1)) * 4;
    const int a1 = a0 + 64;
    const bool ghi = (g >= 2);

    float m = -1e30f, l = 0.f;
    f32x4 o[2];
    o[0] = (f32x4){0.f, 0.f, 0.f, 0.f};
    o[1] = (f32x4){0.f, 0.f, 0.f, 0.f};

    for (int c = 0; c < 4; ++c) {
        __syncthreads();   // prev-chunk reads (and pel/QPE reads for c=0) done
        // ---- stage K chunk: 128 keys x 32 c, zero-padded OOB ----
        #pragma unroll
        for (int r2 = 0; r2 < 2; ++r2) {
            const int idx = r2*256 + tid;
            const int key = idx >> 2, part = idx & 3;
            const int hz = key >> 6, hy = (key >> 3) & 7, hx = key & 7;
            const int gz = tz*4 - 2 + 2*c + hz, gy = ty*4 - 2 + hy,
                      gx = tx*4 - 2 + hx;
            floatx4 kv = (floatx4){0.f, 0.f, 0.f, 0.f};
            if ((unsigned)gz < 32u && (unsigned)gy < 32u && (unsigned)gx < 32u)
                kv = *(const floatx4*)
                     &kT[(hb + gz*1024 + gy*32 + gx)*NHD + part*8];
            *(floatx4*)&kl[key][part*8] = kv;
        }
        // ---- stage V^T chunk: key-pair packed b32 writes (conflict-free) ----
        {
            const int kp = tid & 63, hdo = tid >> 6;
            const int aK = 2*kp;                 // even key; pair never
            const int hz = aK >> 6;              // straddles a halo row
            const int hy = (aK >> 3) & 7, hx = aK & 7;
            const int gz = tz*4 - 2 + 2*c + hz, gy = ty*4 - 2 + hy,
                      gx = tx*4 - 2 + hx;
            const bool vzy = ((unsigned)gz < 32u) && ((unsigned)gy < 32u);
            B8 va, vb;
            va.v = (floatx4){0.f, 0.f, 0.f, 0.f};
            vb.v = (floatx4){0.f, 0.f, 0.f, 0.f};
            const size_t gb = hb + gz*1024 + gy*32;
            if (vzy && (unsigned)gx < 32u)
                va.v = *(const floatx4*)&vT[(gb + gx)*NHD + hdo*8];
            if (vzy && (unsigned)(gx + 1) < 32u)
                vb.v = *(const floatx4*)&vT[(gb + gx + 1)*NHD + hdo*8];
            #pragma unroll
            for (int i = 0; i < 8; ++i) {
                const unsigned u = (unsigned)va.h[i] | ((unsigned)vb.h[i] << 16);
                *(unsigned*)&vtl[hdo*8 + i][aK] = u;
            }
        }
        __syncthreads();   // chunk staged

        #pragma unroll
        for (int zl = 0; zl < 2; ++zl) {
            const int dz = 2*c + zl - wave;       // wave-uniform
            if ((unsigned)dz > 4u) continue;      // skip invalid z layer
            const int nz = dz * 25;
            // ---- S^T tile = K . Q^T (4 MFMAs, 64 keys) ----
            f32x4 s[4];
            __builtin_amdgcn_s_setprio(1);
            #pragma unroll
            for (int tt = 0; tt < 4; ++tt) {
                bf16x8 ka = *(const bf16x8*)&kl[zl*64 + tt*16 + m16][g*8];
                s[tt] = __builtin_amdgcn_mfma_f32_16x16x32_bf16(
                    ka, bq, (f32x4){0.f, 0.f, 0.f, 0.f}, 0, 0, 0);
            }
            __builtin_amdgcn_s_setprio(0);
            // ---- biased+masked scores (log2 domain), layer max ----
            float mx = -1e30f;
            #pragma unroll
            for (int tt = 0; tt < 4; ++tt) {
                #pragma unroll
                for (int r = 0; r < 4; ++r) {
                    const unsigned n =
                        min((unsigned)nz + ((nopk[tt] >> (8*r)) & 255u), 128u);
                    const float qb  = b2f(qprow[n]);   // -inf when masked
                    const float val = fmaf(s[tt][r], SL_F, qb);
                    s[tt][r] = val;
                    mx = fmaxf(mx, val);
                }
            }
            mx = fmaxf(mx, __shfl_xor(mx, 16));
            mx = fmaxf(mx, __shfl_xor(mx, 32));
            const float mn = fmaxf(m, mx);
            const float al = exp2f(m - mn);
            m = mn;
            // ---- P = exp2(S - m), bf16-packed in registers ----
            float ls = 0.f;
            unsigned pk[4][2];
            #pragma unroll
            for (int tt = 0; tt < 4; ++tt) {
                const float p0 = exp2f(s[tt][0] - mn);
                const float p1 = exp2f(s[tt][1] - mn);
                const float p2 = exp2f(s[tt][2] - mn);
                const float p3 = exp2f(s[tt][3] - mn);
                ls += (p0 + p1) + (p2 + p3);
                pk[tt][0] = (unsigned)f2b(p0) | ((unsigned)f2b(p1) << 16);
                pk[tt][1] = (unsigned)f2b(p2) | ((unsigned)f2b(p3) << 16);
            }
            ls += __shfl_xor(ls, 16);
            ls += __shfl_xor(ls, 32);
            l = l * al + ls;
            #pragma unroll
            for (int i = 0; i < 4; ++i) { o[0][i] *= al; o[1][i] *= al; }
            // ---- O^T += V^T . P^T; P B-frag via bpermute ----
            // lane (m16,g) needs P[q=m16][k=ksl*32+g*8+j]; key K: tile
            // tt=2*ksl+(g>>1), word (w&1), src lane m16+16*(2*(g&1)+(w>>1)).
            #pragma unroll
            for (int ksl = 0; ksl < 2; ++ksl) {
                union { unsigned u[4]; bf16x8 v; } pb;
                #pragma unroll
                for (int w = 0; w < 4; ++w) {
                    const int ad = (w < 2) ? a0 : a1;
                    const int wi = w & 1;
                    const int lo = __builtin_amdgcn_ds_bpermute(
                        ad, (int)pk[2*ksl][wi]);
                    const int hi = __builtin_amdgcn_ds_bpermute(
                        ad, (int)pk[2*ksl + 1][wi]);
                    pb.u[w] = ghi ? (unsigned)hi : (unsigned)lo;
                }
                __builtin_amdgcn_s_setprio(1);
                #pragma unroll
                for (int mt = 0; mt < 2; ++mt) {
                    bf16x8 va = *(const bf16x8*)
                        &vtl[mt*16 + m16][zl*64 + ksl*32 + g*8];
                    o[mt] = __builtin_amdgcn_mfma_f32_16x16x32_bf16(
                        va, pb.v, o[mt], 0, 0, 0);
                }
                __builtin_amdgcn_s_setprio(0);
            }
        }
    }

    // ---- normalize + store: lane holds O^T[hd = mt*16+g4+r][q = wq] ----
    const float rl = 1.f / l;
    const size_t sq = (size_t)(tz*4 + wave)*1024 + (ty*4 + qy)*32 + (tx*4 + qx);
    #pragma unroll
    for (int mt = 0; mt < 2; ++mt) {
        const unsigned w0 = (unsigned)f2b(o[mt][0]*rl) |
                            ((unsigned)f2b(o[mt][1]*rl) << 16);
        const unsigned w1 = (unsigned)f2b(o[mt][2]*rl) |
                            ((unsigned)f2b(o[mt][3]*rl) << 16);
        *(uint2*)&aT[(hb + sq)*NHD + mt*16 + g4] = make_uint2(w0, w1);
    }
}

// ---------------------------------------------------------------------------
// Kernel 3: proj GEMM, MFMA. grid (256 s-tiles, 3 o-tiles), 256 threads.
// ---------------------------------------------------------------------------
__global__ __launch_bounds__(256) void proj_mfma(
    const bfr* __restrict__ aT, const float* __restrict__ w,
    const float* __restrict__ bias, float* __restrict__ out)
{
    __shared__ __attribute__((aligned(16))) bfr wl[128*40];   // [o][c] pad40
    __shared__ __attribute__((aligned(16))) bfr xl[128*40];   // [s][c] pad40
    __shared__ float bsh[128];
    const int tid  = threadIdx.x;
    const int lane = tid & 63;
    const int wave = tid >> 6;
    const int wo   = (wave & 1) * 64;
    const int wsq  = (wave >> 1) * 64;
    const int s0   = blockIdx.x * 128;
    const int o0   = blockIdx.y * 128;
    const int m16  = lane & 15;
    const int g    = lane >> 4;

    if (tid < 128) bsh[tid] = bias[o0 + tid];

    f32x4 acc[4][4];
    #pragma unroll
    for (int i = 0; i < 4; ++i)
        #pragma unroll
        for (int j = 0; j < 4; ++j) acc[i][j] = (f32x4){0.f, 0.f, 0.f, 0.f};

    for (int kc = 0; kc < 12; ++kc) {          // kc == head
        const int c0 = kc * 32;
        // stage w tile [128 o][32 c] f32->bf16
        #pragma unroll
        for (int r = 0; r < 4; ++r) {
            const int idx = r*256 + tid;
            const int o   = idx >> 3;
            const int c4  = (idx & 7) * 4;
            floatx4 wv = *(const floatx4*)&w[(size_t)(o0 + o)*NC + c0 + c4];
            short4v t;
            t[0] = (short)f2b(wv[0]); t[1] = (short)f2b(wv[1]);
            t[2] = (short)f2b(wv[2]); t[3] = (short)f2b(wv[3]);
            *(short4v*)&wl[o*40 + c4] = t;
        }
        // stage a tile: [128 s][32 c] bf16, direct b128 copies (512, 2/thread)
        #pragma unroll
        for (int r = 0; r < 2; ++r) {
            const int idx = r*256 + tid;
            const int s   = idx >> 2;
            const int gg  = idx & 3;
            *(floatx4*)&xl[s*40 + gg*8] =
                *(const floatx4*)&aT[((size_t)kc*NS + s0 + s)*NHD + gg*8];
        }
        __syncthreads();
        bf16x8 af[4], bfg[4];
        #pragma unroll
        for (int i = 0; i < 4; ++i)
            af[i] = *(bf16x8*)&wl[(wo + i*16 + m16)*40 + g*8];
        #pragma unroll
        for (int j = 0; j < 4; ++j)
            bfg[j] = *(bf16x8*)&xl[(wsq + j*16 + m16)*40 + g*8];
        #pragma unroll
        for (int i = 0; i < 4; ++i)
            #pragma unroll
            for (int j = 0; j < 4; ++j)
                acc[i][j] = __builtin_amdgcn_mfma_f32_16x16x32_bf16(
                    af[i], bfg[j], acc[i][j], 0, 0, 0);
        __syncthreads();
    }

    // epilogue: +bias, f32 channel-major out[o][s]
    const int q4 = g * 4;
    #pragma unroll
    for (int i = 0; i < 4; ++i) {
        const int olb = wo + i*16 + q4;
        #pragma unroll
        for (int j = 0; j < 4; ++j) {
            const int s = s0 + wsq + j*16 + m16;
            #pragma unroll
            for (int r = 0; r < 4; ++r)
                out[(size_t)(o0 + olb + r)*NS + s] = acc[i][j][r] + bsh[olb + r];
        }
    }
}

// ---------------------------------------------------------------------------
extern "C" void kernel_launch(void* const* d_in, const int* in_sizes, int n_in,
                              void* d_out, int out_size, void* d_ws, size_t ws_size,
                              hipStream_t stream)
{
    const float* x      = (const float*)d_in[0];
    const float* w_qkv  = (const float*)d_in[1];
    const float* b_qkv  = (const float*)d_in[2];
    const float* w_proj = (const float*)d_in[3];
    const float* b_proj = (const float*)d_in[4];
    const float* pe     = (const float*)d_in[5];
    float* outp = (float*)d_out;

    const size_t NEED = (size_t)2 * PERB * sizeof(bfr);  // 48 MiB
    if (ws_size < NEED) {
        fill_code<<<2048, 256, 0, stream>>>(outp, (float)(ws_size >> 20));
        return;
    }

    bfr* qT = (bfr*)d_ws;          // ws[0 .. PERB)      (aT aliases this)
    bfr* vT = qT + PERB;           // ws[PERB .. 2*PERB)

    for (int b = 0; b < NB; ++b) {
        bfr* kT = (bfr*)(outp + (size_t)b * PERB);  // d_out batch half
        bfr* aT = qT;
        qkv_mfma<<<dim3(256, 9, 1), 256, 0, stream>>>(
            x, w_qkv, b_qkv, qT, kT, vT, b);
        attn3d<<<dim3(512, 12, 1), 256, 0, stream>>>(qT, kT, vT, pe, aT);
        proj_mfma<<<dim3(256, 3, 1), 256, 0, stream>>>(
            aT, w_proj, b_proj, outp + (size_t)b * PERB);
    }
}